// Round 15
// baseline (58.306 us; speedup 1.0000x reference)
//
#include <hip/hip_runtime.h>
#include <hip/hip_bf16.h>
#include <math.h>

#define NB 32      // B
#define NV 1024    // V
#define NFT 16     // F
#define NA 32      // A
#define NP 64      // P
#define NOUT 128   // NF
#define NC 96      // C = P + A
#define NC2 192    // 2C

#define NSPLIT 16            // V splits
#define VPB 64               // rows per block

typedef __attribute__((ext_vector_type(8))) short bf16x8;
typedef __attribute__((ext_vector_type(4))) float f32x4;

// ---------------------------------------------------------------------------
// K2p: DIAGNOSTIC x3 REPEAT of the R9 body (best-measured config).
// Each rep re-reads inputs and rewrites identical values (deterministic).
// dur_us delta vs R14 gives 2x k2p_interior; the x3 dispatch surfaces in
// rocprof top-5 with real counters for this kernel.
// ---------------------------------------------------------------------------
__global__ __launch_bounds__(512, 2)
void k2p(const float* __restrict__ x,
         const float* __restrict__ W_flr,
         const float* __restrict__ b_flr,
         const float* __restrict__ W_s,
         const float* __restrict__ b_s,
         float* __restrict__ ewbuf,
         float* __restrict__ part) {
    __shared__ float xs[VPB][NFT];        // 4 KB
    __shared__ float fs[VPB][NC];         // 24 KB

    int b = blockIdx.x, vs = blockIdx.y, tid = threadIdx.x;
    int rowbase = b * NV + vs * VPB;

    for (int rep = 0; rep < 3; ++rep) {
        // stage x: 1024 floats = 256 float4
        if (tid < 256) {
            const float4* xsrc = (const float4*)(x + (size_t)rowbase * NFT);
            ((float4*)xs)[tid] = xsrc[tid];
        }
        __syncthreads();

        // phase A: c = tid&127 (<96 active), rh = tid>>7 -> rows rh*16..+15
        {
            int c  = tid & 127;
            int rh = tid >> 7;
            if (c < NC) {
                float Wcol[NFT], bias;
                if (c < NP) {
                    bias = b_flr[c];
#pragma unroll
                    for (int k = 0; k < NFT; ++k) Wcol[k] = W_flr[k * NP + c];
                } else {
                    int a = c - NP;
                    bias = b_s[a];
#pragma unroll
                    for (int k = 0; k < NFT; ++k) Wcol[k] = W_s[k * NA + a];
                }
#pragma unroll
                for (int r0 = 0; r0 < 16; ++r0) {
                    int r = rh * 16 + r0;
                    float xr[NFT];
#pragma unroll
                    for (int q = 0; q < 4; ++q)
                        ((float4*)xr)[q] = ((const float4*)xs[r])[q];
                    float acc = bias;
#pragma unroll
                    for (int k = 0; k < NFT; ++k)
                        acc = fmaf(xr[k], Wcol[k], acc);
                    if (c >= NP) {
                        acc = __expf(-acc * acc);
                        ewbuf[(size_t)(rowbase + r) * NA + (c - NP)] = acc;
                    }
                    fs[r][c] = acc;
                }
            }
        }
        __syncthreads();

        // phase B: thread owns 1a x 6c over all 64 rows
        int a  = tid >> 4;
        int c0 = (tid & 15) * 6;
        int ea = NP + a;

        float sm[6], mx[6];
#pragma unroll
        for (int j = 0; j < 6; ++j) { sm[j] = 0.f; mx[j] = -INFINITY; }

#pragma unroll 4
        for (int r = 0; r < VPB; ++r) {
            float e = fs[r][ea];
            float2 fA = *(const float2*)&fs[r][c0];
            float2 fB = *(const float2*)&fs[r][c0 + 2];
            float2 fC = *(const float2*)&fs[r][c0 + 4];
            float ff[6] = {fA.x, fA.y, fB.x, fB.y, fC.x, fC.y};
#pragma unroll
            for (int j = 0; j < 6; ++j) {
                float p = e * ff[j];
                sm[j] += p;
                mx[j] = fmaxf(mx[j], p);
            }
        }

        float* pb = part + (size_t)((b * NSPLIT + vs) * NA + a) * NC2;
#pragma unroll
        for (int q = 0; q < 3; ++q) {
            float2 vm = {mx[2 * q], mx[2 * q + 1]};
            float2 vsum = {sm[2 * q], sm[2 * q + 1]};
            *(float2*)&pb[c0 + 2 * q]      = vm;
            *(float2*)&pb[NC + c0 + 2 * q] = vsum;
        }
        __syncthreads();   // separate this rep's fs reads from next rep's writes
    }
}

// ---------------------------------------------------------------------------
// K23: combine NSPLIT partials -> agg (LDS) -> G matmul. (unchanged)
// ---------------------------------------------------------------------------
__global__ void k23(const float* __restrict__ part,
                    const float* __restrict__ W_out,
                    float* __restrict__ Gp) {
    __shared__ float aggL[NC2];
    int b = blockIdx.x, a = blockIdx.y, tid = threadIdx.x;

    {
        const float* pb = part + (size_t)(b * NSPLIT * NA + a) * NC2 + tid;
        const size_t stride = (size_t)NA * NC2;
        if (tid < NC) {
            float m = -INFINITY;
#pragma unroll
            for (int vsi = 0; vsi < NSPLIT; ++vsi)
                m = fmaxf(m, pb[vsi * stride]);
            aggL[tid] = m;
        } else {
            float s = 0.f;
#pragma unroll
            for (int vsi = 0; vsi < NSPLIT; ++vsi)
                s += pb[vsi * stride];
            aggL[tid] = s * (1.0f / (float)NV);
        }
    }
    __syncthreads();

    if (tid < NOUT) {
        int n = tid;
        const float* wr = W_out + (size_t)(NFT + a * NC2) * NOUT + n;
        float acc = W_out[(size_t)(NFT + NA * NC2 + a) * NOUT + n];
#pragma unroll 8
        for (int c = 0; c < NC2; ++c)
            acc = fmaf(aggL[c], wr[(size_t)c * NOUT], acc);
        Gp[(size_t)(b * NA + a) * NOUT + n] = acc;
    }
}

// ---------------------------------------------------------------------------
// K4 (MFMA, conflict-free fragment-order layout). (unchanged)
// ---------------------------------------------------------------------------
#define MB 64

__device__ inline void f2hl(float v, ushort& h, ushort& l) {
    __hip_bfloat16 hb = __float2bfloat16(v);
    float hf = __bfloat162float(hb);
    __hip_bfloat16 lb = __float2bfloat16(v - hf);
    h = *(ushort*)&hb;
    l = *(ushort*)&lb;
}

__global__ void k4_mfma(const float* __restrict__ x,
                        const float* __restrict__ ewbuf,
                        const float* __restrict__ Gp,
                        const float* __restrict__ W_out,
                        const float* __restrict__ b_out,
                        float* __restrict__ out) {
    __shared__ ushort BsH[1024 * 8];   // 16 KB
    __shared__ ushort BsL[1024 * 8];   // 16 KB
    __shared__ float  bs[NOUT];

    int rb = blockIdx.x;
    int b  = blockIdx.y;
    int tid = threadIdx.x;
    int rowbase = b * NV + rb * MB;

    // ---- stage B in fragment-order ----
#pragma unroll
    for (int it = 0; it < 4; ++it) {
        int u = it * 256 + tid;
        int n = u & 127, koct = u >> 7;
        float v[8];
        if (koct < 2) {
#pragma unroll
            for (int j = 0; j < 8; ++j)
                v[j] = W_out[(size_t)(koct * 8 + j) * NOUT + n];
        } else if (koct < 6) {
#pragma unroll
            for (int j = 0; j < 8; ++j)
                v[j] = Gp[(size_t)b * NA * NOUT + (size_t)(koct * 8 + j - 16) * NOUT + n];
        } else {
#pragma unroll
            for (int j = 0; j < 8; ++j) v[j] = 0.f;
        }
        ushort h[8], l[8];
#pragma unroll
        for (int j = 0; j < 8; ++j) f2hl(v[j], h[j], l[j]);
        int cidx = ((koct >> 2) * 512) + ((n >> 4) * 64) + ((koct & 3) * 16) + (n & 15);
        *(bf16x8*)&BsH[cidx * 8] = *(bf16x8*)h;
        *(bf16x8*)&BsL[cidx * 8] = *(bf16x8*)l;
    }
    if (tid < NOUT) bs[tid] = b_out[tid];

    // ---- A fragments direct from global ----
    int w = tid >> 6, lane = tid & 63;
    int r16 = lane & 15, kg = lane >> 4;
    int arow = w * 16 + r16;
    int grow = rowbase + arow;

    float a0[8], a1[8];
    if (kg < 2) {
        *(float4*)&a0[0] = *(const float4*)&x[(size_t)grow * NFT + kg * 8];
        *(float4*)&a0[4] = *(const float4*)&x[(size_t)grow * NFT + kg * 8 + 4];
        *(float4*)&a1[0] = *(const float4*)&ewbuf[(size_t)grow * NA + 16 + kg * 8];
        *(float4*)&a1[4] = *(const float4*)&ewbuf[(size_t)grow * NA + 16 + kg * 8 + 4];
    } else {
        *(float4*)&a0[0] = *(const float4*)&ewbuf[(size_t)grow * NA + (kg - 2) * 8];
        *(float4*)&a0[4] = *(const float4*)&ewbuf[(size_t)grow * NA + (kg - 2) * 8 + 4];
#pragma unroll
        for (int j = 0; j < 8; ++j) a1[j] = 0.f;
    }
    ushort ah0[8], al0[8], ah1[8], al1[8];
#pragma unroll
    for (int j = 0; j < 8; ++j) f2hl(a0[j], ah0[j], al0[j]);
#pragma unroll
    for (int j = 0; j < 8; ++j) f2hl(a1[j], ah1[j], al1[j]);
    bf16x8 AH0 = *(bf16x8*)ah0, AL0 = *(bf16x8*)al0;
    bf16x8 AH1 = *(bf16x8*)ah1, AL1 = *(bf16x8*)al1;

    __syncthreads();

    int orow0 = rowbase + w * 16 + kg * 4;

#pragma unroll
    for (int nt = 0; nt < 8; ++nt) {
        int n = nt * 16 + r16;
        bf16x8 BH0 = *(const bf16x8*)&BsH[(nt * 64 + lane) * 8];
        bf16x8 BH1 = *(const bf16x8*)&BsH[(512 + nt * 64 + lane) * 8];
        bf16x8 BL0 = *(const bf16x8*)&BsL[(nt * 64 + lane) * 8];
        bf16x8 BL1 = *(const bf16x8*)&BsL[(512 + nt * 64 + lane) * 8];
        float bias = bs[n];
        f32x4 acc = {bias, bias, bias, bias};
        acc = __builtin_amdgcn_mfma_f32_16x16x32_bf16(AH0, BH0, acc, 0, 0, 0);
        acc = __builtin_amdgcn_mfma_f32_16x16x32_bf16(AL0, BH0, acc, 0, 0, 0);
        acc = __builtin_amdgcn_mfma_f32_16x16x32_bf16(AH0, BL0, acc, 0, 0, 0);
        acc = __builtin_amdgcn_mfma_f32_16x16x32_bf16(AH1, BH1, acc, 0, 0, 0);
        acc = __builtin_amdgcn_mfma_f32_16x16x32_bf16(AL1, BH1, acc, 0, 0, 0);
        acc = __builtin_amdgcn_mfma_f32_16x16x32_bf16(AH1, BL1, acc, 0, 0, 0);
#pragma unroll
        for (int rg = 0; rg < 4; ++rg) {
            float s = acc[rg];
            s = fminf(fmaxf(s, -15.f), 15.f);
            float e = __expf(2.f * s);
            out[(size_t)(orow0 + rg) * NOUT + n] =
                (e - 1.f) * __builtin_amdgcn_rcpf(e + 1.f);
        }
    }
}

// ---------------------------------------------------------------------------
extern "C" void kernel_launch(void* const* d_in, const int* in_sizes, int n_in,
                              void* d_out, int out_size, void* d_ws, size_t ws_size,
                              hipStream_t stream) {
    const float* x     = (const float*)d_in[0];
    const float* W_flr = (const float*)d_in[1];
    const float* b_flr = (const float*)d_in[2];
    const float* W_s   = (const float*)d_in[3];
    const float* b_s   = (const float*)d_in[4];
    const float* W_out = (const float*)d_in[5];
    const float* b_out = (const float*)d_in[6];
    float* out = (float*)d_out;

    // workspace layout (floats)
    float* ewbuf = (float*)d_ws;                              // B*V*32     = 1,048,576
    float* part  = ewbuf + (size_t)NB * NV * NA;              // 512*32*192 = 3,145,728
    float* Gp    = part  + (size_t)NB * NSPLIT * NA * NC2;    // B*A*128    =   131,072

    // K2p (x3 diagnostic): grid (B, 16) x 512
    {
        dim3 g(NB, NSPLIT);
        k2p<<<g, 512, 0, stream>>>(x, W_flr, b_flr, W_s, b_s, ewbuf, part);
    }
    // K23: grid (B, A) x 192
    {
        dim3 g(NB, NA);
        k23<<<g, 192, 0, stream>>>(part, W_out, Gp);
    }
    // K4: grid (16 row-blocks, B) x 256
    {
        dim3 g(NV / MB, NB);
        k4_mfma<<<g, 256, 0, stream>>>(x, ewbuf, Gp, W_out, b_out, out);
    }
}